// Round 1
// baseline (736.886 us; speedup 1.0000x reference)
//
#include <hip/hip_runtime.h>
#include <hip/hip_bf16.h>
#include <stdint.h>

// Problem constants
#define B_   2
#define S_   1024
#define HS_  1024
#define H_   16
#define D_   64
#define V_   1025   // vocab = 2*512+1
#define VP_  1056   // vocab padded to multiple of 32
#define BH_  32     // B_*H_

typedef __attribute__((ext_vector_type(8))) short  short8;
typedef __attribute__((ext_vector_type(4))) short  short4v;
typedef __attribute__((ext_vector_type(4))) float  floatx4;
typedef __attribute__((ext_vector_type(4))) int    intx4;
typedef __bf16 bf16x8 __attribute__((ext_vector_type(8)));

// f32 -> bf16 (RNE), bit pattern as short
__device__ inline short f2b(float f) {
  union { float f; uint32_t u; } c; c.f = f;
  uint32_t u = c.u;
  uint32_t r = (u + 0x7fffu + ((u >> 16) & 1u)) >> 16;
  return (short)r;
}
__device__ inline float b2f(short s) {
  union { uint32_t u; float f; } c; c.u = ((uint32_t)(uint16_t)s) << 16;
  return c.f;
}
// load 8 f32 (32B) and convert to bf16x8 (as short8)
__device__ inline short8 cvt8(const float* p) {
  const floatx4* p4 = reinterpret_cast<const floatx4*>(p);
  floatx4 x = p4[0], y = p4[1];
  short8 r;
  r[0]=f2b(x[0]); r[1]=f2b(x[1]); r[2]=f2b(x[2]); r[3]=f2b(x[3]);
  r[4]=f2b(y[0]); r[5]=f2b(y[1]); r[6]=f2b(y[2]); r[7]=f2b(y[3]);
  return r;
}
__device__ inline short8 load_s8(const short* p) {
  return *reinterpret_cast<const short8*>(p);
}
__device__ inline floatx4 mfma16(short8 a, short8 b, floatx4 c) {
  return __builtin_amdgcn_mfma_f32_16x16x32_bf16(
      __builtin_bit_cast(bf16x8, a), __builtin_bit_cast(bf16x8, b), c, 0, 0, 0);
}

// ---------------------------------------------------------------------------
// K0: rveT[d][p] = rve[p][d] as bf16, zero-padded to VP_
__global__ __launch_bounds__(256) void k_rvet(const float* __restrict__ rve,
                                              short* __restrict__ rveT) {
  int idx = blockIdx.x * 256 + threadIdx.x;   // D_*VP_ = 67584
  if (idx >= D_ * VP_) return;
  int d = idx / VP_, p = idx % VP_;
  float v = (p < V_) ? rve[p * D_ + d] : 0.f;
  rveT[d * VP_ + p] = f2b(v);
}

// ---------------------------------------------------------------------------
// K1: projections. which=0: qh = q@Wq^T+bq (bf16, (B*S,HS))
//                  which=1: kh          (bf16, (B*S,HS))
//                  which=2: vhT[b][h][d][s]  (bf16)
__global__ __launch_bounds__(256) void k_proj(
    const float* __restrict__ qi, const float* __restrict__ ki, const float* __restrict__ vi,
    const float* __restrict__ Wq, const float* __restrict__ bq,
    const float* __restrict__ Wk, const float* __restrict__ bk,
    const float* __restrict__ Wv, const float* __restrict__ bv,
    short* __restrict__ qh, short* __restrict__ kh, short* __restrict__ vhT) {
  int which = blockIdx.z;
  const float* X = which == 0 ? qi : which == 1 ? ki : vi;
  const float* W = which == 0 ? Wq : which == 1 ? Wk : Wv;
  const float* bias = which == 0 ? bq : which == 1 ? bk : bv;
  int m0 = blockIdx.y * 64, n0 = blockIdx.x * 64;
  int tid = threadIdx.x, wave = tid >> 6, lane = tid & 63;
  int qd = lane >> 4, c16 = lane & 15;
  __shared__ short Wl[64][40];   // 64 n-rows x 32 k, pad to 40 shorts
  floatx4 acc[4] = {};
  int mrow = m0 + wave * 16 + c16;
  const float* arow = X + (size_t)mrow * HS_ + qd * 8;
  int sn = tid >> 2, sk = (tid & 3) * 8;
  const float* wrow = W + (size_t)(n0 + sn) * HS_ + sk;
  for (int kc = 0; kc < HS_; kc += 32) {
    short8 wsv = cvt8(wrow + kc);
    *reinterpret_cast<short8*>(&Wl[sn][sk]) = wsv;
    __syncthreads();
    short8 a = cvt8(arow + kc);
#pragma unroll
    for (int nt = 0; nt < 4; nt++) {
      short8 b = *reinterpret_cast<const short8*>(&Wl[nt * 16 + c16][qd * 8]);
      acc[nt] = mfma16(a, b, acc[nt]);
    }
    __syncthreads();
  }
#pragma unroll
  for (int nt = 0; nt < 4; nt++) {
    int col = n0 + nt * 16 + c16;
    float bsum = bias[col];
    if (which < 2) {
      short* dst = which == 0 ? qh : kh;
#pragma unroll
      for (int r = 0; r < 4; r++) {
        int row = m0 + wave * 16 + qd * 4 + r;
        dst[(size_t)row * HS_ + col] = f2b(acc[nt][r] + bsum);
      }
    } else {
      int h = col >> 6, d = col & 63;
      int srow = m0 + wave * 16 + qd * 4;   // 4 consecutive s values
      int bb = srow >> 10, s = srow & 1023;
      short4v pk;
#pragma unroll
      for (int r = 0; r < 4; r++) pk[r] = f2b(acc[nt][r] + bsum);
      *reinterpret_cast<short4v*>(&vhT[(((size_t)(bb * H_ + h)) * D_ + d) * S_ + s]) = pk;
    }
  }
}

// ---------------------------------------------------------------------------
// K2: R[bh][q][p] = qh[b,q,h*64:..] . rke[p,:]   (bf16 out, p-stride VP_)
__global__ __launch_bounds__(256) void k_relkey(
    const short* __restrict__ qh, const float* __restrict__ rke, short* __restrict__ R) {
  int bh = blockIdx.z;
  int b = bh >> 4, h = bh & 15;
  int q0 = blockIdx.y * 64;
  int tid = threadIdx.x, wave = tid >> 6, lane = tid & 63;
  int qd = lane >> 4, c16 = lane & 15;
  int p0 = blockIdx.x * 64 + wave * 16;
  int prow = p0 + c16;
  short8 b0 = {}, b1 = {};
  if (prow < V_) {
    b0 = cvt8(rke + prow * D_ + qd * 8);
    b1 = cvt8(rke + prow * D_ + 32 + qd * 8);
  }
  short* Rbase = R + (size_t)bh * S_ * VP_;
#pragma unroll
  for (int qs = 0; qs < 4; qs++) {
    const short* ap = qh + ((size_t)b * S_ + q0 + qs * 16 + c16) * HS_ + h * 64 + qd * 8;
    floatx4 acc = {};
    acc = mfma16(load_s8(ap), b0, acc);
    acc = mfma16(load_s8(ap + 32), b1, acc);
    int p = p0 + c16;
    if (p < VP_) {
#pragma unroll
      for (int r = 0; r < 4; r++) {
        int qrow = q0 + qs * 16 + qd * 4 + r;
        Rbase[(size_t)qrow * VP_ + p] = f2b(acc[r]);
      }
    }
  }
}

// ---------------------------------------------------------------------------
// K3: fused attention for one (b,h,q-tile of 16):
//  logits(LDS) -> softmax -> weights(d_out) + hist(LDS scatter) -> ctx_rel = hist@rveT
__global__ __launch_bounds__(256) void k_attn(
    const short* __restrict__ qh, const short* __restrict__ kh,
    const short* __restrict__ R, const int* __restrict__ rp,
    const short* __restrict__ rveT, float* __restrict__ weights,
    float* __restrict__ ctx_rel) {
  int bh = blockIdx.y;
  int b = bh >> 4, h = bh & 15;
  int q0 = blockIdx.x * 16;
  int tid = threadIdx.x, wave = tid >> 6, lane = tid & 63;
  int qd = lane >> 4, c16 = lane & 15;
  __shared__ float L[16][1028];      // logits/weights tile (pad: stride%32==4)
  __shared__ float hist[16][1060];   // vocab histogram (stride%32==4)
  __shared__ float rowInv[16];
  // zero hist
  for (int i = tid; i < 16 * 1060; i += 256) (&hist[0][0])[i] = 0.f;
  // phase 1: logits = qh.kh^T + R[gather rp]
  const short* aptr = qh + ((size_t)b * S_ + q0 + c16) * HS_ + h * 64 + qd * 8;
  short8 a0 = load_s8(aptr), a1 = load_s8(aptr + 32);
  const short* Rrow = R + (size_t)bh * S_ * VP_;
  for (int it = 0; it < 16; it++) {
    int c0 = wave * 256 + it * 16;
    const short* bptr = kh + ((size_t)b * S_ + c0 + c16) * HS_ + h * 64 + qd * 8;
    floatx4 acc = {};
    acc = mfma16(a0, load_s8(bptr), acc);
    acc = mfma16(a1, load_s8(bptr + 32), acc);
    int col = c0 + c16;
#pragma unroll
    for (int r = 0; r < 4; r++) {
      int qr = qd * 4 + r;
      int p = rp[(size_t)(q0 + qr) * S_ + col];
      float rel = b2f(Rrow[(size_t)(q0 + qr) * VP_ + p]);
      L[qr][col] = acc[r] + rel;
    }
  }
  __syncthreads();
  // phase 2: per-row softmax stats; wave w handles rows 4w..4w+3
  for (int rr = 0; rr < 4; rr++) {
    int row = wave * 4 + rr;
    float m = -1e30f;
    for (int c = lane; c < S_; c += 64) m = fmaxf(m, L[row][c]);
#pragma unroll
    for (int off = 32; off > 0; off >>= 1) m = fmaxf(m, __shfl_xor(m, off));
    float s = 0.f;
    for (int c = lane; c < S_; c += 64) {
      float e = __expf(L[row][c] - m);
      L[row][c] = e;
      s += e;
    }
#pragma unroll
    for (int off = 32; off > 0; off >>= 1) s += __shfl_xor(s, off);
    if (lane == 0) rowInv[row] = 1.f / s;
  }
  __syncthreads();
  // phase 3: write weights + scatter into hist
  float* wout = weights + (size_t)bh * S_ * S_ + (size_t)q0 * S_;
  for (int row = 0; row < 16; row++) {
    int c = tid * 4;
    float inv = rowInv[row];
    floatx4 w4 = *reinterpret_cast<floatx4*>(&L[row][c]);
    w4 *= inv;
    *reinterpret_cast<floatx4*>(&wout[(size_t)row * S_ + c]) = w4;
    intx4 p4 = *reinterpret_cast<const intx4*>(&rp[(size_t)(q0 + row) * S_ + c]);
    atomicAdd(&hist[row][p4[0]], w4[0]);
    atomicAdd(&hist[row][p4[1]], w4[1]);
    atomicAdd(&hist[row][p4[2]], w4[2]);
    atomicAdd(&hist[row][p4[3]], w4[3]);
  }
  __syncthreads();
  // phase 4: ctx_rel[16 q][64 d] = hist @ rve  (B from rveT rows)
  {
    int d0 = wave * 16;
    floatx4 acc = {};
    for (int kc = 0; kc < VP_; kc += 32) {
      short8 a = cvt8(&hist[c16][kc + qd * 8]);
      short8 bfr = load_s8(rveT + (size_t)(d0 + c16) * VP_ + kc + qd * 8);
      acc = mfma16(a, bfr, acc);
    }
    float* cr = ctx_rel + ((size_t)b * S_ + q0) * HS_ + h * 64 + d0;
#pragma unroll
    for (int r = 0; r < 4; r++) {
      int qr = qd * 4 + r;
      cr[(size_t)qr * HS_ + c16] = acc[r];
    }
  }
}

// ---------------------------------------------------------------------------
// K4: ctx[b,q,h*64+d] = weights @ vh + ctx_rel   (bf16 out)
__global__ __launch_bounds__(256) void k_ctx(
    const float* __restrict__ weights, const short* __restrict__ vhT,
    const float* __restrict__ ctx_rel, short* __restrict__ ctx) {
  int bh = blockIdx.y;
  int b = bh >> 4, h = bh & 15;
  int q0 = blockIdx.x * 64;
  int tid = threadIdx.x, wave = tid >> 6, lane = tid & 63;
  int qd = lane >> 4, c16 = lane & 15;
  __shared__ short Vl[64][40];
  floatx4 acc[4] = {};
  const float* wrow = weights + ((size_t)bh * S_ + q0 + wave * 16 + c16) * S_ + qd * 8;
  int sd = tid >> 2, sk = (tid & 3) * 8;
  const short* vrow = vhT + ((size_t)bh * D_ + sd) * S_ + sk;
  for (int kc = 0; kc < S_; kc += 32) {
    *reinterpret_cast<short8*>(&Vl[sd][sk]) = load_s8(vrow + kc);
    __syncthreads();
    short8 a = cvt8(wrow + kc);
#pragma unroll
    for (int nt = 0; nt < 4; nt++) {
      short8 bfr = *reinterpret_cast<const short8*>(&Vl[nt * 16 + c16][qd * 8]);
      acc[nt] = mfma16(a, bfr, acc[nt]);
    }
    __syncthreads();
  }
#pragma unroll
  for (int nt = 0; nt < 4; nt++) {
    int d = nt * 16 + c16;
#pragma unroll
    for (int r = 0; r < 4; r++) {
      int q = q0 + wave * 16 + qd * 4 + r;
      size_t off = ((size_t)b * S_ + q) * HS_ + h * 64 + d;
      ctx[off] = f2b(acc[nt][r] + ctx_rel[off]);
    }
  }
}

// ---------------------------------------------------------------------------
// K5: out0 = ctx @ Wo^T + bo   (f32)
__global__ __launch_bounds__(256) void k_oproj(
    const short* __restrict__ ctx, const float* __restrict__ Wo,
    const float* __restrict__ bo, float* __restrict__ out0) {
  int m0 = blockIdx.y * 64, n0 = blockIdx.x * 64;
  int tid = threadIdx.x, wave = tid >> 6, lane = tid & 63;
  int qd = lane >> 4, c16 = lane & 15;
  __shared__ short Wl[64][40];
  floatx4 acc[4] = {};
  const short* arow = ctx + (size_t)(m0 + wave * 16 + c16) * HS_ + qd * 8;
  int sn = tid >> 2, sk = (tid & 3) * 8;
  const float* wrow = Wo + (size_t)(n0 + sn) * HS_ + sk;
  for (int kc = 0; kc < HS_; kc += 32) {
    short8 wsv = cvt8(wrow + kc);
    *reinterpret_cast<short8*>(&Wl[sn][sk]) = wsv;
    __syncthreads();
    short8 a = load_s8(arow + kc);
#pragma unroll
    for (int nt = 0; nt < 4; nt++) {
      short8 b = *reinterpret_cast<const short8*>(&Wl[nt * 16 + c16][qd * 8]);
      acc[nt] = mfma16(a, b, acc[nt]);
    }
    __syncthreads();
  }
#pragma unroll
  for (int nt = 0; nt < 4; nt++) {
    int col = n0 + nt * 16 + c16;
    float bsum = bo[col];
#pragma unroll
    for (int r = 0; r < 4; r++) {
      int row = m0 + wave * 16 + qd * 4 + r;
      out0[(size_t)row * HS_ + col] = acc[nt][r] + bsum;
    }
  }
}

// ---------------------------------------------------------------------------
// K6: out = LayerNorm(out0 + residual) * g + b
__global__ __launch_bounds__(256) void k_ln(
    const float* __restrict__ out0, const float* __restrict__ resid,
    const float* __restrict__ g, const float* __restrict__ bb,
    float* __restrict__ out) {
  int row = blockIdx.x;
  int tid = threadIdx.x, wave = tid >> 6, lane = tid & 63;
  const floatx4* x4 = reinterpret_cast<const floatx4*>(out0 + (size_t)row * HS_);
  const floatx4* r4 = reinterpret_cast<const floatx4*>(resid + (size_t)row * HS_);
  floatx4 x = x4[tid] + r4[tid];
  float s = x[0] + x[1] + x[2] + x[3];
  float ss = x[0]*x[0] + x[1]*x[1] + x[2]*x[2] + x[3]*x[3];
  __shared__ float red[8];
#pragma unroll
  for (int off = 32; off > 0; off >>= 1) {
    s += __shfl_xor(s, off);
    ss += __shfl_xor(ss, off);
  }
  if (lane == 0) { red[wave] = s; red[wave + 4] = ss; }
  __syncthreads();
  s = red[0] + red[1] + red[2] + red[3];
  ss = red[4] + red[5] + red[6] + red[7];
  float mu = s * (1.f / 1024.f);
  float var = ss * (1.f / 1024.f) - mu * mu;
  float rs = rsqrtf(var + 1e-5f);
  int c = tid * 4;
  floatx4 gg = *reinterpret_cast<const floatx4*>(g + c);
  floatx4 bv = *reinterpret_cast<const floatx4*>(bb + c);
  floatx4 y = (x - mu) * rs * gg + bv;
  reinterpret_cast<floatx4*>(out + (size_t)row * HS_)[tid] = y;
}

// ---------------------------------------------------------------------------
extern "C" void kernel_launch(void* const* d_in, const int* in_sizes, int n_in,
                              void* d_out, int out_size, void* d_ws, size_t ws_size,
                              hipStream_t stream) {
  const float* q   = (const float*)d_in[0];
  const float* k   = (const float*)d_in[1];
  const float* v   = (const float*)d_in[2];
  const int*   rp  = (const int*)d_in[3];
  const float* Wq  = (const float*)d_in[4];
  const float* bq  = (const float*)d_in[5];
  const float* Wk  = (const float*)d_in[6];
  const float* bk  = (const float*)d_in[7];
  const float* Wv  = (const float*)d_in[8];
  const float* bv  = (const float*)d_in[9];
  const float* rke = (const float*)d_in[10];
  const float* rve = (const float*)d_in[11];
  const float* Wo  = (const float*)d_in[12];
  const float* bo  = (const float*)d_in[13];
  const float* lng = (const float*)d_in[14];
  const float* lnb = (const float*)d_in[15];

  float* out = (float*)d_out;                         // (B,S,HS) f32
  float* weights = out + (size_t)B_ * S_ * HS_;       // (B,H,S,S) f32

  // workspace layout (bytes); total = 102,895,616
  char* ws = (char*)d_ws;
  short* qh      = (short*)(ws);                      //  4 MB bf16 (B*S,HS)
  short* kh      = (short*)(ws + 4194304);            //  4 MB
  short* vhT     = (short*)(ws + 8388608);            //  4 MB (B,H,D,S)
  short* ctx     = (short*)(ws + 12582912);           //  4 MB (B,S,HS)
  short* rveT    = (short*)(ws + 16777216);           //  132 KB (D,VP)
  float* ctx_rel = (float*)(ws + 16912384);           //  8 MB f32 (B,S,HS)
  float* out0    = (float*)(ws + 25300992);           //  8 MB f32
  short* R       = (short*)(ws + 33689600);           //  66 MB bf16 (BH,S,VP)

  k_rvet  <<<dim3(264),        256, 0, stream>>>(rve, rveT);
  k_proj  <<<dim3(16, 32, 3),  256, 0, stream>>>(q, k, v, Wq, bq, Wk, bk, Wv, bv, qh, kh, vhT);
  k_relkey<<<dim3(17, 16, 32), 256, 0, stream>>>(qh, rke, R);
  k_attn  <<<dim3(64, 32),     256, 0, stream>>>(qh, kh, R, rp, rveT, weights, ctx_rel);
  k_ctx   <<<dim3(16, 32),     256, 0, stream>>>(weights, vhT, ctx_rel, ctx);
  k_oproj <<<dim3(16, 32),     256, 0, stream>>>(ctx, Wo, bo, out0);
  k_ln    <<<dim3(2048),       256, 0, stream>>>(out0, q, lng, lnb, out);
}

// Round 3
// 566.664 us; speedup vs baseline: 1.3004x; 1.3004x over previous
//
#include <hip/hip_runtime.h>
#include <hip/hip_bf16.h>
#include <stdint.h>

// Problem constants
#define B_   2
#define S_   1024
#define HS_  1024
#define H_   16
#define D_   64
#define V_   1025   // vocab = 2*512+1
#define VP_  1056   // vocab padded to multiple of 32
#define BH_  32     // B_*H_
#define RTS_ 1060   // LDS row stride for Rtile/hist (f32): 4*1060%32==16 -> no 4-way

typedef __attribute__((ext_vector_type(8))) short  short8;
typedef __attribute__((ext_vector_type(4))) short  short4v;
typedef __attribute__((ext_vector_type(4))) float  floatx4;
typedef __attribute__((ext_vector_type(4))) int    intx4;
typedef __bf16 bf16x8 __attribute__((ext_vector_type(8)));

// f32 -> bf16 (RNE), bit pattern as short
__device__ inline short f2b(float f) {
  union { float f; uint32_t u; } c; c.f = f;
  uint32_t u = c.u;
  uint32_t r = (u + 0x7fffu + ((u >> 16) & 1u)) >> 16;
  return (short)r;
}
__device__ inline float b2f(short s) {
  union { uint32_t u; float f; } c; c.u = ((uint32_t)(uint16_t)s) << 16;
  return c.f;
}
// load 8 f32 (32B) and convert to bf16x8 (as short8)
__device__ inline short8 cvt8(const float* p) {
  const floatx4* p4 = reinterpret_cast<const floatx4*>(p);
  floatx4 x = p4[0], y = p4[1];
  short8 r;
  r[0]=f2b(x[0]); r[1]=f2b(x[1]); r[2]=f2b(x[2]); r[3]=f2b(x[3]);
  r[4]=f2b(y[0]); r[5]=f2b(y[1]); r[6]=f2b(y[2]); r[7]=f2b(y[3]);
  return r;
}
__device__ inline short8 load_s8(const short* p) {
  return *reinterpret_cast<const short8*>(p);
}
__device__ inline floatx4 mfma16(short8 a, short8 b, floatx4 c) {
  return __builtin_amdgcn_mfma_f32_16x16x32_bf16(
      __builtin_bit_cast(bf16x8, a), __builtin_bit_cast(bf16x8, b), c, 0, 0, 0);
}

// ---------------------------------------------------------------------------
// K0: prep embeddings:
//   rveT[d][p] = rve[p][d] bf16, zero-padded p in [V_,VP_)
//   rkeB[p][d] = rke[p][d] bf16
__global__ __launch_bounds__(256) void k_prep(const float* __restrict__ rve,
                                              const float* __restrict__ rke,
                                              short* __restrict__ rveT,
                                              short* __restrict__ rkeB) {
  int idx = blockIdx.x * 256 + threadIdx.x;
  if (idx < D_ * VP_) {
    int d = idx / VP_, p = idx % VP_;
    float v = (p < V_) ? rve[p * D_ + d] : 0.f;
    rveT[d * VP_ + p] = f2b(v);
  } else {
    int j = idx - D_ * VP_;
    if (j < V_ * D_) rkeB[j] = f2b(rke[j]);
  }
}

// ---------------------------------------------------------------------------
// K1: projections. which=0: qh = q@Wq^T+bq (bf16, (B*S,HS))
//                  which=1: kh          (bf16, (B*S,HS))
//                  which=2: vhT[b][h][d][s]  (bf16)
__global__ __launch_bounds__(256) void k_proj(
    const float* __restrict__ qi, const float* __restrict__ ki, const float* __restrict__ vi,
    const float* __restrict__ Wq, const float* __restrict__ bq,
    const float* __restrict__ Wk, const float* __restrict__ bk,
    const float* __restrict__ Wv, const float* __restrict__ bv,
    short* __restrict__ qh, short* __restrict__ kh, short* __restrict__ vhT) {
  int which = blockIdx.z;
  const float* X = which == 0 ? qi : which == 1 ? ki : vi;
  const float* W = which == 0 ? Wq : which == 1 ? Wk : Wv;
  const float* bias = which == 0 ? bq : which == 1 ? bk : bv;
  int m0 = blockIdx.y * 64, n0 = blockIdx.x * 64;
  int tid = threadIdx.x, wave = tid >> 6, lane = tid & 63;
  int qd = lane >> 4, c16 = lane & 15;
  __shared__ short Wl[64][40];   // 64 n-rows x 32 k, pad to 40 shorts
  floatx4 acc[4] = {};
  int mrow = m0 + wave * 16 + c16;
  const float* arow = X + (size_t)mrow * HS_ + qd * 8;
  int sn = tid >> 2, sk = (tid & 3) * 8;
  const float* wrow = W + (size_t)(n0 + sn) * HS_ + sk;
  for (int kc = 0; kc < HS_; kc += 32) {
    short8 wsv = cvt8(wrow + kc);
    *reinterpret_cast<short8*>(&Wl[sn][sk]) = wsv;
    __syncthreads();
    short8 a = cvt8(arow + kc);
#pragma unroll
    for (int nt = 0; nt < 4; nt++) {
      short8 b = *reinterpret_cast<const short8*>(&Wl[nt * 16 + c16][qd * 8]);
      acc[nt] = mfma16(a, b, acc[nt]);
    }
    __syncthreads();
  }
#pragma unroll
  for (int nt = 0; nt < 4; nt++) {
    int col = n0 + nt * 16 + c16;
    float bsum = bias[col];
    if (which < 2) {
      short* dst = which == 0 ? qh : kh;
#pragma unroll
      for (int r = 0; r < 4; r++) {
        int row = m0 + wave * 16 + qd * 4 + r;
        dst[(size_t)row * HS_ + col] = f2b(acc[nt][r] + bsum);
      }
    } else {
      int h = col >> 6, d = col & 63;
      int srow = m0 + wave * 16 + qd * 4;   // 4 consecutive s values
      int bb = srow >> 10, s = srow & 1023;
      short4v pk;
#pragma unroll
      for (int r = 0; r < 4; r++) pk[r] = f2b(acc[nt][r] + bsum);
      *reinterpret_cast<short4v*>(&vhT[(((size_t)(bb * H_ + h)) * D_ + d) * S_ + s]) = pk;
    }
  }
}

// ---------------------------------------------------------------------------
// K3: fused attention for one (b,h, 16-q tile):
//  P0: Rtile[16][1056] = qh_tile @ rkeB^T  (LDS, f32)
//  P1: logits (registers) = qh.kh^T + Rtile[rp gather]
//  P2: softmax in registers (shfl + tiny LDS cross-wave reduce)
//  P3: write weights (global) + scatter into hist (LDS, same region as Rtile)
//  P4: ctx_rel = hist @ rveT
__global__ __launch_bounds__(256, 2) void k_attn(
    const short* __restrict__ qh, const short* __restrict__ kh,
    const short* __restrict__ rkeB, const int* __restrict__ rp,
    const short* __restrict__ rveT, float* __restrict__ weights,
    float* __restrict__ ctx_rel) {
  int bh = blockIdx.y;
  int b = bh >> 4, h = bh & 15;
  int q0 = blockIdx.x * 16;
  int tid = threadIdx.x, wave = tid >> 6, lane = tid & 63;
  int qd = lane >> 4, c16 = lane & 15;
  __shared__ float RtH[16 * RTS_];   // Rtile (P0-P1), then hist (P3-P4)
  __shared__ float redA[4 * 16];
  __shared__ float redB[4 * 16];

  // A-fragments for the 16 q rows (shared by P0 and P1)
  const short* aptr = qh + ((size_t)b * S_ + q0 + c16) * HS_ + h * 64 + qd * 8;
  short8 a0 = load_s8(aptr), a1 = load_s8(aptr + 32);

  // ---- P0: Rtile = qh_tile(16x64) @ rkeB^T(64x1056) -> LDS f32
  for (int nt = wave; nt < VP_ / 16; nt += 4) {
    int p = nt * 16 + c16;
    short8 b0 = {}, b1 = {};
    if (p < V_) {
      b0 = load_s8(rkeB + (size_t)p * D_ + qd * 8);
      b1 = load_s8(rkeB + (size_t)p * D_ + 32 + qd * 8);
    }
    floatx4 acc = {};
    acc = mfma16(a0, b0, acc);
    acc = mfma16(a1, b1, acc);
#pragma unroll
    for (int r = 0; r < 4; r++) RtH[(qd * 4 + r) * RTS_ + p] = acc[r];
  }
  __syncthreads();

  // ---- P1: logits in registers
  floatx4 acc[16];
  const int* rpq = rp + (size_t)q0 * S_;
#pragma unroll
  for (int it = 0; it < 16; it++) {
    int col = wave * 256 + it * 16 + c16;
    const short* bptr = kh + ((size_t)b * S_ + col) * HS_ + h * 64 + qd * 8;
    floatx4 a = {};
    a = mfma16(a0, load_s8(bptr), a);
    a = mfma16(a1, load_s8(bptr + 32), a);
#pragma unroll
    for (int r = 0; r < 4; r++) {
      int row = qd * 4 + r;
      int p = rpq[(size_t)row * S_ + col];
      a[r] += RtH[row * RTS_ + p];
    }
    acc[it] = a;
  }
  __syncthreads();   // all Rtile reads done; region may be reused

  // ---- P2: softmax over registers
  float mx[4], inv[4];
#pragma unroll
  for (int r = 0; r < 4; r++) {
    float m = -1e30f;
#pragma unroll
    for (int it = 0; it < 16; it++) m = fmaxf(m, acc[it][r]);
#pragma unroll
    for (int off = 1; off < 16; off <<= 1) m = fmaxf(m, __shfl_xor(m, off));
    mx[r] = m;
    if (c16 == 0) redA[wave * 16 + qd * 4 + r] = m;
  }
  __syncthreads();
#pragma unroll
  for (int r = 0; r < 4; r++) {
    int row = qd * 4 + r;
    float m = fmaxf(fmaxf(redA[row], redA[16 + row]),
                    fmaxf(redA[32 + row], redA[48 + row]));
    mx[r] = m;
  }
  float sm[4] = {0.f, 0.f, 0.f, 0.f};
#pragma unroll
  for (int it = 0; it < 16; it++) {
#pragma unroll
    for (int r = 0; r < 4; r++) {
      float e = __expf(acc[it][r] - mx[r]);
      acc[it][r] = e;
      sm[r] += e;
    }
  }
#pragma unroll
  for (int r = 0; r < 4; r++) {
#pragma unroll
    for (int off = 1; off < 16; off <<= 1) sm[r] += __shfl_xor(sm[r], off);
    if (c16 == 0) redB[wave * 16 + qd * 4 + r] = sm[r];
  }
  __syncthreads();
#pragma unroll
  for (int r = 0; r < 4; r++) {
    int row = qd * 4 + r;
    inv[r] = 1.f / (redB[row] + redB[16 + row] + redB[32 + row] + redB[48 + row]);
  }
  // zero hist (same region as Rtile)
  for (int i = tid; i < 16 * RTS_; i += 256) RtH[i] = 0.f;
  __syncthreads();

  // ---- P3: write weights + scatter into hist
  float* wout = weights + (size_t)bh * S_ * S_ + (size_t)q0 * S_;
#pragma unroll
  for (int it = 0; it < 16; it++) {
    int col = wave * 256 + it * 16 + c16;
#pragma unroll
    for (int r = 0; r < 4; r++) {
      int row = qd * 4 + r;
      float w = acc[it][r] * inv[r];
      wout[(size_t)row * S_ + col] = w;
      int p = rpq[(size_t)row * S_ + col];
      atomicAdd(&RtH[row * RTS_ + p], w);
    }
  }
  __syncthreads();

  // ---- P4: ctx_rel[16 q][64 d] = hist @ rveT
  {
    int d0 = wave * 16;
    floatx4 a4 = {};
    for (int kc = 0; kc < VP_; kc += 32) {
      short8 a = cvt8(&RtH[c16 * RTS_ + kc + qd * 8]);
      short8 bfr = load_s8(rveT + (size_t)(d0 + c16) * VP_ + kc + qd * 8);
      a4 = mfma16(a, bfr, a4);
    }
    float* cr = ctx_rel + ((size_t)b * S_ + q0) * HS_ + h * 64 + d0;
#pragma unroll
    for (int r = 0; r < 4; r++) {
      int qr = qd * 4 + r;
      cr[(size_t)qr * HS_ + c16] = a4[r];
    }
  }
}

// ---------------------------------------------------------------------------
// K4: ctx[b,q,h*64+d] = weights @ vh + ctx_rel   (bf16 out)
__global__ __launch_bounds__(256) void k_ctx(
    const float* __restrict__ weights, const short* __restrict__ vhT,
    const float* __restrict__ ctx_rel, short* __restrict__ ctx) {
  int bh = blockIdx.y;
  int b = bh >> 4, h = bh & 15;
  int q0 = blockIdx.x * 64;
  int tid = threadIdx.x, wave = tid >> 6, lane = tid & 63;
  int qd = lane >> 4, c16 = lane & 15;
  __shared__ short Vl[64][40];
  floatx4 acc[4] = {};
  const float* wrow = weights + ((size_t)bh * S_ + q0 + wave * 16 + c16) * S_ + qd * 8;
  int sd = tid >> 2, sk = (tid & 3) * 8;
  const short* vrow = vhT + ((size_t)bh * D_ + sd) * S_ + sk;
  for (int kc = 0; kc < S_; kc += 32) {
    *reinterpret_cast<short8*>(&Vl[sd][sk]) = load_s8(vrow + kc);
    __syncthreads();
    short8 a = cvt8(wrow + kc);
#pragma unroll
    for (int nt = 0; nt < 4; nt++) {
      short8 bfr = *reinterpret_cast<const short8*>(&Vl[nt * 16 + c16][qd * 8]);
      acc[nt] = mfma16(a, bfr, acc[nt]);
    }
    __syncthreads();
  }
#pragma unroll
  for (int nt = 0; nt < 4; nt++) {
    int d = nt * 16 + c16;
#pragma unroll
    for (int r = 0; r < 4; r++) {
      int q = q0 + wave * 16 + qd * 4 + r;
      size_t off = ((size_t)b * S_ + q) * HS_ + h * 64 + d;
      ctx[off] = f2b(acc[nt][r] + ctx_rel[off]);
    }
  }
}

// ---------------------------------------------------------------------------
// K5: out0 = ctx @ Wo^T + bo   (f32)
__global__ __launch_bounds__(256) void k_oproj(
    const short* __restrict__ ctx, const float* __restrict__ Wo,
    const float* __restrict__ bo, float* __restrict__ out0) {
  int m0 = blockIdx.y * 64, n0 = blockIdx.x * 64;
  int tid = threadIdx.x, wave = tid >> 6, lane = tid & 63;
  int qd = lane >> 4, c16 = lane & 15;
  __shared__ short Wl[64][40];
  floatx4 acc[4] = {};
  const short* arow = ctx + (size_t)(m0 + wave * 16 + c16) * HS_ + qd * 8;
  int sn = tid >> 2, sk = (tid & 3) * 8;
  const float* wrow = Wo + (size_t)(n0 + sn) * HS_ + sk;
  for (int kc = 0; kc < HS_; kc += 32) {
    short8 wsv = cvt8(wrow + kc);
    *reinterpret_cast<short8*>(&Wl[sn][sk]) = wsv;
    __syncthreads();
    short8 a = load_s8(arow + kc);
#pragma unroll
    for (int nt = 0; nt < 4; nt++) {
      short8 b = *reinterpret_cast<const short8*>(&Wl[nt * 16 + c16][qd * 8]);
      acc[nt] = mfma16(a, b, acc[nt]);
    }
    __syncthreads();
  }
#pragma unroll
  for (int nt = 0; nt < 4; nt++) {
    int col = n0 + nt * 16 + c16;
    float bsum = bo[col];
#pragma unroll
    for (int r = 0; r < 4; r++) {
      int row = m0 + wave * 16 + qd * 4 + r;
      out0[(size_t)row * HS_ + col] = acc[nt][r] + bsum;
    }
  }
}

// ---------------------------------------------------------------------------
// K6: out = LayerNorm(out0 + residual) * g + b
__global__ __launch_bounds__(256) void k_ln(
    const float* __restrict__ out0, const float* __restrict__ resid,
    const float* __restrict__ g, const float* __restrict__ bb,
    float* __restrict__ out) {
  int row = blockIdx.x;
  int tid = threadIdx.x, wave = tid >> 6, lane = tid & 63;
  const floatx4* x4 = reinterpret_cast<const floatx4*>(out0 + (size_t)row * HS_);
  const floatx4* r4 = reinterpret_cast<const floatx4*>(resid + (size_t)row * HS_);
  floatx4 x = x4[tid] + r4[tid];
  float s = x[0] + x[1] + x[2] + x[3];
  float ss = x[0]*x[0] + x[1]*x[1] + x[2]*x[2] + x[3]*x[3];
  __shared__ float red[8];
#pragma unroll
  for (int off = 32; off > 0; off >>= 1) {
    s += __shfl_xor(s, off);
    ss += __shfl_xor(ss, off);
  }
  if (lane == 0) { red[wave] = s; red[wave + 4] = ss; }
  __syncthreads();
  s = red[0] + red[1] + red[2] + red[3];
  ss = red[4] + red[5] + red[6] + red[7];
  float mu = s * (1.f / 1024.f);
  float var = ss * (1.f / 1024.f) - mu * mu;
  float rs = rsqrtf(var + 1e-5f);
  int c = tid * 4;
  floatx4 gg = *reinterpret_cast<const floatx4*>(g + c);
  floatx4 bv = *reinterpret_cast<const floatx4*>(bb + c);
  floatx4 y = (x - mu) * rs * gg + bv;
  reinterpret_cast<floatx4*>(out + (size_t)row * HS_)[tid] = y;
}

// ---------------------------------------------------------------------------
extern "C" void kernel_launch(void* const* d_in, const int* in_sizes, int n_in,
                              void* d_out, int out_size, void* d_ws, size_t ws_size,
                              hipStream_t stream) {
  const float* q   = (const float*)d_in[0];
  const float* k   = (const float*)d_in[1];
  const float* v   = (const float*)d_in[2];
  const int*   rp  = (const int*)d_in[3];
  const float* Wq  = (const float*)d_in[4];
  const float* bq  = (const float*)d_in[5];
  const float* Wk  = (const float*)d_in[6];
  const float* bk  = (const float*)d_in[7];
  const float* Wv  = (const float*)d_in[8];
  const float* bv  = (const float*)d_in[9];
  const float* rke = (const float*)d_in[10];
  const float* rve = (const float*)d_in[11];
  const float* Wo  = (const float*)d_in[12];
  const float* bo  = (const float*)d_in[13];
  const float* lng = (const float*)d_in[14];
  const float* lnb = (const float*)d_in[15];

  float* out = (float*)d_out;                         // (B,S,HS) f32
  float* weights = out + (size_t)B_ * S_ * HS_;       // (B,H,S,S) f32

  // workspace layout (bytes) — offsets audited for non-overlap:
  //   qh      [ 0        ,  4194304)
  //   kh      [ 4194304  ,  8388608)
  //   vhT     [ 8388608  , 12582912)
  //   ctx     [12582912  , 16777216)
  //   rveT    [16777216  , 16912384)   D_*VP_*2  = 135168
  //   rkeB    [16912384  , 17043584)   V_*D_*2   = 131200
  //   ctx_rel [17043968  , 25432576)   8 MB      (256-aligned, AFTER rkeB end!)
  //   out0    [25432576  , 33821184)   8 MB
  char* ws = (char*)d_ws;
  short* qh      = (short*)(ws);
  short* kh      = (short*)(ws + 4194304);
  short* vhT     = (short*)(ws + 8388608);
  short* ctx     = (short*)(ws + 12582912);
  short* rveT    = (short*)(ws + 16777216);
  short* rkeB    = (short*)(ws + 16912384);
  float* ctx_rel = (float*)(ws + 17043968);
  float* out0    = (float*)(ws + 25432576);

  k_prep  <<<dim3(521),        256, 0, stream>>>(rve, rke, rveT, rkeB);
  k_proj  <<<dim3(16, 32, 3),  256, 0, stream>>>(q, k, v, Wq, bq, Wk, bk, Wv, bv, qh, kh, vhT);
  k_attn  <<<dim3(64, 32),     256, 0, stream>>>(qh, kh, rkeB, rp, rveT, weights, ctx_rel);
  k_ctx   <<<dim3(16, 32),     256, 0, stream>>>(weights, vhT, ctx_rel, ctx);
  k_oproj <<<dim3(16, 32),     256, 0, stream>>>(ctx, Wo, bo, out0);
  k_ln    <<<dim3(2048),       256, 0, stream>>>(out0, q, lng, lnb, out);
}